// Round 1
// baseline (1944.619 us; speedup 1.0000x reference)
//
#include <hip/hip_runtime.h>
#include <float.h>
#include <math.h>

constexpr int NN = 50000;
constexpr int NE = 800000;
constexpr int DD = 128;
constexpr float AVG_D_LOG_F = 2.833f;
constexpr float EPS_F = 1e-5f;

__device__ __forceinline__ unsigned f2ord(float x) {
    unsigned u = __float_as_uint(x);
    return (u & 0x80000000u) ? ~u : (u | 0x80000000u);
}
__device__ __forceinline__ float ord2f(unsigned u) {
    unsigned b = (u & 0x80000000u) ? (u ^ 0x80000000u) : ~u;
    return __uint_as_float(b);
}

// ---------------- K0: init accumulators ----------------
__global__ void k_init(float* __restrict__ sum, float* __restrict__ sumsq,
                       unsigned* __restrict__ mxu, unsigned* __restrict__ mnu,
                       unsigned* __restrict__ deg) {
    int i = blockIdx.x * blockDim.x + threadIdx.x;
    const int total = NN * DD;
    for (; i < total; i += gridDim.x * blockDim.x) {
        sum[i] = 0.f;
        sumsq[i] = 0.f;
        mxu[i] = 0x007FFFFFu;  // ord(-inf)
        mnu[i] = 0xFF800000u;  // ord(+inf)
        if (i < NN) deg[i] = 0u;
    }
}

// ---------------- K1: P1 = h @ W_pre[0:128], P2 = h @ W_pre[128:256] ----------------
__global__ __launch_bounds__(256) void k_p12(const float* __restrict__ h,
                                             const float* __restrict__ Wpre,
                                             float* __restrict__ P1,
                                             float* __restrict__ P2) {
    __shared__ float4 hs[8][32];
    const int t = threadIdx.x;
    const int base = blockIdx.x * 8;
    {
        int r = t >> 5, q = t & 31;
        hs[r][q] = ((const float4*)h)[(size_t)(base + r) * 32 + q];
    }
    __syncthreads();
    const int col = t & 127, rh = t >> 7;
    float acc1[4] = {0.f, 0.f, 0.f, 0.f};
    float acc2[4] = {0.f, 0.f, 0.f, 0.f};
    for (int k = 0; k < DD; k += 4) {
        float w1[4], w2[4];
#pragma unroll
        for (int j = 0; j < 4; j++) {
            w1[j] = Wpre[(k + j) * DD + col];
            w2[j] = Wpre[(DD + k + j) * DD + col];
        }
#pragma unroll
        for (int rr = 0; rr < 4; rr++) {
            float4 z = hs[rh + rr * 2][k >> 2];
            acc1[rr] += z.x * w1[0] + z.y * w1[1] + z.z * w1[2] + z.w * w1[3];
            acc2[rr] += z.x * w2[0] + z.y * w2[1] + z.z * w2[2] + z.w * w2[3];
        }
    }
#pragma unroll
    for (int rr = 0; rr < 4; rr++) {
        size_t n = (size_t)(base + rh + rr * 2);
        P1[n * DD + col] = acc1[rr];
        P2[n * DD + col] = acc2[rr];
    }
}

// ---------------- K2: per-edge m = e@W3 + b + P1[src] + P2[dst]; atomic reduce ----------------
__global__ __launch_bounds__(256) void k_edge(const float* __restrict__ e,
                                              const int* __restrict__ src,
                                              const int* __restrict__ dst,
                                              const float* __restrict__ Wpre,
                                              const float* __restrict__ bpre,
                                              const float* __restrict__ P1,
                                              const float* __restrict__ P2,
                                              float* __restrict__ sum,
                                              float* __restrict__ sumsq,
                                              unsigned* __restrict__ mxu,
                                              unsigned* __restrict__ mnu,
                                              unsigned* __restrict__ deg) {
    __shared__ float4 es[32][32];
    __shared__ int sid[32], did[32];
    const int t = threadIdx.x;
    const size_t base = (size_t)blockIdx.x * 32;
#pragma unroll
    for (int j = 0; j < 4; j++) {
        int idx = t + 256 * j;
        int r = idx >> 5, q = idx & 31;
        es[r][q] = ((const float4*)e)[(base + r) * 32 + q];
    }
    if (t < 32) {
        int s_ = src[base + t];
        int d_ = dst[base + t];
        sid[t] = s_;
        did[t] = d_;
        atomicAdd(&deg[d_], 1u);
    }
    __syncthreads();
    const int col = t & 127, esub = t >> 7;
    float acc[16];
#pragma unroll
    for (int i = 0; i < 16; i++) acc[i] = 0.f;
    for (int k = 0; k < DD; k += 4) {
        float w[4];
#pragma unroll
        for (int j = 0; j < 4; j++) w[j] = Wpre[(256 + k + j) * DD + col];
#pragma unroll
        for (int i = 0; i < 16; i++) {
            float4 z = es[esub * 16 + i][k >> 2];
            acc[i] += z.x * w[0] + z.y * w[1] + z.z * w[2] + z.w * w[3];
        }
    }
    const float bp = bpre[col];
    for (int i = 0; i < 16; i++) {
        int le = esub * 16 + i;
        int s_ = sid[le], d_ = did[le];
        float m = acc[i] + bp + P1[(size_t)s_ * DD + col] + P2[(size_t)d_ * DD + col];
        size_t o = (size_t)d_ * DD + col;
        atomicAdd(&sum[o], m);
        atomicAdd(&sumsq[o], m * m);
        atomicMax(&mxu[o], f2ord(m));
        atomicMin(&mnu[o], f2ord(m));
    }
}

// ---------------- K3: posttrans out = [h|scaled] @ W_post + b, * snorm ----------------
__global__ __launch_bounds__(256) void k_post(const float* __restrict__ h,
                                              const float* __restrict__ snorm,
                                              const float* __restrict__ Wpost,
                                              const float* __restrict__ bpost,
                                              const float* __restrict__ sum,
                                              const float* __restrict__ sumsq,
                                              const unsigned* __restrict__ mxu,
                                              const unsigned* __restrict__ mnu,
                                              const unsigned* __restrict__ deg,
                                              float* __restrict__ out) {
    __shared__ float xs[8][1664];
    const int t = threadIdx.x;
    const int base = blockIdx.x * 8;
    for (int idx = t; idx < 8 * DD; idx += 256) {
        int r = idx >> 7, c = idx & 127;
        int n = base + r;
        unsigned dg = deg[n];
        float degf = (float)dg;
        float degsafe = fmaxf(degf, 1.f);
        size_t o = (size_t)n * DD + c;
        float s = sum[o], s2 = sumsq[o];
        float mean = s / degsafe;
        float var = fmaxf(s2 / degsafe - mean * mean, 0.f);
        float sd = sqrtf(var + EPS_F);
        bool has = dg > 0u;
        float msk = has ? 1.f : 0.f;
        float a0 = mean * msk;
        float a1 = has ? ord2f(mxu[o]) : 0.f;
        float a2 = has ? ord2f(mnu[o]) : 0.f;
        float a3 = sd * msk;
        float amp = logf(degf + 1.f) * (1.f / AVG_D_LOG_F);
        float att = AVG_D_LOG_F / logf(degsafe + 1.f);
        xs[r][c] = h[(size_t)n * DD + c];
        xs[r][128 + c] = a0;
        xs[r][256 + c] = a1;
        xs[r][384 + c] = a2;
        xs[r][512 + c] = a3;
        xs[r][640 + c] = a0 * amp;
        xs[r][768 + c] = a1 * amp;
        xs[r][896 + c] = a2 * amp;
        xs[r][1024 + c] = a3 * amp;
        xs[r][1152 + c] = a0 * att;
        xs[r][1280 + c] = a1 * att;
        xs[r][1408 + c] = a2 * att;
        xs[r][1536 + c] = a3 * att;
    }
    __syncthreads();
    const int col = t & 127, rh = t >> 7;
    float acc[4] = {0.f, 0.f, 0.f, 0.f};
    for (int k = 0; k < 1664; k += 4) {
        float w[4];
#pragma unroll
        for (int j = 0; j < 4; j++) w[j] = Wpost[(k + j) * DD + col];
#pragma unroll
        for (int rr = 0; rr < 4; rr++) {
            float4 z = *reinterpret_cast<const float4*>(&xs[rh + rr * 2][k]);
            acc[rr] += z.x * w[0] + z.y * w[1] + z.z * w[2] + z.w * w[3];
        }
    }
#pragma unroll
    for (int rr = 0; rr < 4; rr++) {
        int n = base + rh + rr * 2;
        out[(size_t)n * DD + col] = (acc[rr] + bpost[col]) * snorm[n];
    }
}

extern "C" void kernel_launch(void* const* d_in, const int* in_sizes, int n_in,
                              void* d_out, int out_size, void* d_ws, size_t ws_size,
                              hipStream_t stream) {
    const float* h = (const float*)d_in[0];
    const float* e = (const float*)d_in[1];
    const float* snorm = (const float*)d_in[2];
    const int* src = (const int*)d_in[3];
    const int* dst = (const int*)d_in[4];
    const float* Wpre = (const float*)d_in[5];
    const float* bpre = (const float*)d_in[6];
    const float* Wpost = (const float*)d_in[7];
    const float* bpost = (const float*)d_in[8];
    float* out = (float*)d_out;

    char* ws = (char*)d_ws;
    const size_t nd = (size_t)NN * DD;
    float* P1 = (float*)ws;        ws += nd * 4;
    float* P2 = (float*)ws;        ws += nd * 4;
    float* sum = (float*)ws;       ws += nd * 4;
    float* sumsq = (float*)ws;     ws += nd * 4;
    unsigned* mxu = (unsigned*)ws; ws += nd * 4;
    unsigned* mnu = (unsigned*)ws; ws += nd * 4;
    unsigned* deg = (unsigned*)ws; ws += (size_t)NN * 4;

    k_init<<<25000, 256, 0, stream>>>(sum, sumsq, mxu, mnu, deg);
    k_p12<<<NN / 8, 256, 0, stream>>>(h, Wpre, P1, P2);
    k_edge<<<NE / 32, 256, 0, stream>>>(e, src, dst, Wpre, bpre, P1, P2,
                                        sum, sumsq, mxu, mnu, deg);
    k_post<<<NN / 8, 256, 0, stream>>>(h, snorm, Wpost, bpost,
                                       sum, sumsq, mxu, mnu, deg, out);
}

// Round 2
// 838.418 us; speedup vs baseline: 2.3194x; 2.3194x over previous
//
#include <hip/hip_runtime.h>
#include <math.h>

#define NNODES 50000
#define NEDGES 800000
#define AVGDLOG 2.833f
#define EPSF 1e-5f

typedef __attribute__((ext_vector_type(8))) short short8;
typedef __attribute__((ext_vector_type(4))) float f32x4;

__device__ __forceinline__ unsigned f2bf(float x) {
    unsigned u = __float_as_uint(x);
    return (u + 0x7FFFu + ((u >> 16) & 1u)) >> 16;  // RNE, low 16 bits
}
__device__ __forceinline__ float bf2f(unsigned lo16) {
    return __uint_as_float(lo16 << 16);
}

// ---------- CSR build ----------
__global__ void k_zero(unsigned* __restrict__ deg) {
    int i = blockIdx.x * 256 + threadIdx.x;
    if (i < NNODES) deg[i] = 0u;
}

__global__ void k_count(const int* __restrict__ dst, unsigned* __restrict__ deg) {
    int i = blockIdx.x * 256 + threadIdx.x;
    if (i < NEDGES) atomicAdd(&deg[dst[i]], 1u);
}

__global__ __launch_bounds__(1024) void k_scan(const unsigned* __restrict__ deg,
                                               int* __restrict__ base,
                                               int* __restrict__ cursor) {
    __shared__ int ps[1024];
    const int t = threadIdx.x;
    const int CH = (NNODES + 1023) / 1024;
    int lo = t * CH, hi = min(lo + CH, NNODES);
    int s = 0;
    for (int i = lo; i < hi; ++i) s += (int)deg[i];
    ps[t] = s;
    __syncthreads();
    for (int off = 1; off < 1024; off <<= 1) {
        int v = (t >= off) ? ps[t - off] : 0;
        __syncthreads();
        ps[t] += v;
        __syncthreads();
    }
    int run = (t > 0) ? ps[t - 1] : 0;
    for (int i = lo; i < hi; ++i) {
        base[i] = run; cursor[i] = run;
        run += (int)deg[i];
    }
    if (t == 1023) base[NNODES] = run;
}

__global__ void k_scatter(const int* __restrict__ dst, int* __restrict__ cursor,
                          int* __restrict__ sorted_eid) {
    int i = blockIdx.x * 256 + threadIdx.x;
    if (i < NEDGES) {
        int d = dst[i];
        int slot = atomicAdd(&cursor[d], 1);
        sorted_eid[slot] = i;
    }
}

// ---------- weight conversion: W3t[n][k]=Wpre[256+k][n], Wpt[n][k]=Wpost[k][n] ----------
__global__ void k_convW(const float* __restrict__ Wpre, const float* __restrict__ Wpost,
                        unsigned short* __restrict__ W3t, unsigned short* __restrict__ Wpt) {
    int i = blockIdx.x * 256 + threadIdx.x;
    if (i < 128 * 128) {
        int n = i & 127, k = i >> 7;
        W3t[n * 128 + k] = (unsigned short)f2bf(Wpre[(256 + k) * 128 + n]);
    }
    if (i < 128 * 1664) {
        int n = i & 127, k = i >> 7;
        Wpt[(size_t)n * 1664 + k] = (unsigned short)f2bf(Wpost[k * 128 + n]);
    }
}

// ---------- P1 = h @ Wpre[0:128], P2 = h @ Wpre[128:256]  (bf16 out) ----------
__global__ __launch_bounds__(256) void k_p12(const float* __restrict__ h,
                                             const float* __restrict__ Wpre,
                                             unsigned short* __restrict__ P1,
                                             unsigned short* __restrict__ P2) {
    __shared__ float4 hs[8][32];
    const int t = threadIdx.x;
    const int base = blockIdx.x * 8;
    {
        int r = t >> 5, q = t & 31;
        hs[r][q] = ((const float4*)h)[(size_t)(base + r) * 32 + q];
    }
    __syncthreads();
    const int col = t & 127, rh = t >> 7;
    float acc1[4] = {0.f, 0.f, 0.f, 0.f};
    float acc2[4] = {0.f, 0.f, 0.f, 0.f};
    for (int k = 0; k < 128; k += 4) {
        float w1[4], w2[4];
#pragma unroll
        for (int j = 0; j < 4; j++) {
            w1[j] = Wpre[(k + j) * 128 + col];
            w2[j] = Wpre[(128 + k + j) * 128 + col];
        }
#pragma unroll
        for (int rr = 0; rr < 4; rr++) {
            float4 z = hs[rh + rr * 2][k >> 2];
            acc1[rr] += z.x * w1[0] + z.y * w1[1] + z.z * w1[2] + z.w * w1[3];
            acc2[rr] += z.x * w2[0] + z.y * w2[1] + z.z * w2[2] + z.w * w2[3];
        }
    }
#pragma unroll
    for (int rr = 0; rr < 4; rr++) {
        size_t n = (size_t)(base + rh + rr * 2);
        P1[n * 128 + col] = (unsigned short)f2bf(acc1[rr]);
        P2[n * 128 + col] = (unsigned short)f2bf(acc2[rr]);
    }
}

// ---------- G = bf16(e @ W3 + bpre + P1[src] + P2[dst])  (MFMA) ----------
__global__ __launch_bounds__(256) void k_gemm_e(
    const float* __restrict__ e, const int* __restrict__ src, const int* __restrict__ dst,
    const unsigned short* __restrict__ W3t, const float* __restrict__ bpre,
    const unsigned short* __restrict__ P1, const unsigned short* __restrict__ P2,
    unsigned short* __restrict__ G) {
    __shared__ __align__(16) unsigned short Asm[64 * 128];
    __shared__ __align__(16) unsigned short Bsm[128 * 128];
    __shared__ int Ssrc[64], Sdst[64];
    const int t = threadIdx.x;
    const size_t row0 = (size_t)blockIdx.x * 64;

    // stage B = W3t [n][k], XOR-swizzled (byte ^= (row&7)<<4)
#pragma unroll
    for (int j = 0; j < 16; ++j) {
        int f = t + 256 * j;
        int n = f >> 5, q = f & 31;
        uint2 wv = *(const uint2*)(W3t + n * 128 + q * 4);
        *(uint2*)((char*)Bsm + n * 256 + ((q * 8) ^ ((n & 7) << 4))) = wv;
    }
    // stage A = e tile fp32 -> bf16, swizzled
#pragma unroll
    for (int j = 0; j < 8; ++j) {
        int f = t + 256 * j;
        int r = f >> 5, q = f & 31;
        float4 z = ((const float4*)e)[(row0 + r) * 32 + q];
        uint2 p;
        p.x = f2bf(z.x) | (f2bf(z.y) << 16);
        p.y = f2bf(z.z) | (f2bf(z.w) << 16);
        *(uint2*)((char*)Asm + r * 256 + ((q * 8) ^ ((r & 7) << 4))) = p;
    }
    if (t < 64) { Ssrc[t] = src[row0 + t]; Sdst[t] = dst[row0 + t]; }
    __syncthreads();

    const int w = t >> 6, lane = t & 63;
    const int lrow = lane & 15, lkb = lane >> 4;
    f32x4 acc[8];
#pragma unroll
    for (int i = 0; i < 8; ++i) acc[i] = (f32x4){0.f, 0.f, 0.f, 0.f};

    const char* Abase = (const char*)Asm + (w * 16 + lrow) * 256;
    const unsigned aswz = (unsigned)(((w * 16 + lrow) & 7) << 4);
#pragma unroll
    for (int kk = 0; kk < 4; ++kk) {
        int kbyte = (kk * 32 + lkb * 8) * 2;
        short8 af = *(const short8*)(Abase + (kbyte ^ aswz));
#pragma unroll
        for (int nt = 0; nt < 8; ++nt) {
            int n = nt * 16 + lrow;
            short8 bf = *(const short8*)((const char*)Bsm + n * 256 + (kbyte ^ ((n & 7) << 4)));
            acc[nt] = __builtin_amdgcn_mfma_f32_16x16x32_bf16(af, bf, acc[nt], 0, 0, 0);
        }
    }
#pragma unroll
    for (int nt = 0; nt < 8; ++nt) {
        int c = nt * 16 + lrow;
        float bp = bpre[c];
#pragma unroll
        for (int i = 0; i < 4; ++i) {
            int lr = w * 16 + lkb * 4 + i;
            int s_ = Ssrc[lr], d_ = Sdst[lr];
            float v = acc[nt][i] + bp + bf2f(P1[(size_t)s_ * 128 + c]) + bf2f(P2[(size_t)d_ * 128 + c]);
            G[(row0 + lr) * 128 + c] = (unsigned short)f2bf(v);
        }
    }
}

// ---------- per-node segmented reduce: stats = [mean|max|min|std] bf16 ----------
__global__ __launch_bounds__(256) void k_reduce(
    const unsigned short* __restrict__ G, const int* __restrict__ base,
    const int* __restrict__ sorted_eid, unsigned short* __restrict__ stats) {
    const int t = threadIdx.x;
    const int n = blockIdx.x * 4 + (t >> 6);
    const int lane = t & 63;
    int b0 = base[n], b1 = base[n + 1];
    int dg = b1 - b0;
    float s0 = 0.f, s1 = 0.f, q0 = 0.f, q1 = 0.f;
    float mx0 = -3.4e38f, mx1 = -3.4e38f, mn0 = 3.4e38f, mn1 = 3.4e38f;
    for (int sl = b0; sl < b1; ++sl) {
        int eid = sorted_eid[sl];
        unsigned u = *(const unsigned*)(G + (size_t)eid * 128 + lane * 2);
        float x0 = bf2f(u & 0xffffu), x1 = bf2f(u >> 16);
        s0 += x0; q0 += x0 * x0; mx0 = fmaxf(mx0, x0); mn0 = fminf(mn0, x0);
        s1 += x1; q1 += x1 * x1; mx1 = fmaxf(mx1, x1); mn1 = fminf(mn1, x1);
    }
    float m0, m1, sd0, sd1, X0, X1, N0, N1;
    if (dg > 0) {
        float ds = (float)dg;
        m0 = s0 / ds; m1 = s1 / ds;
        float v0 = fmaxf(q0 / ds - m0 * m0, 0.f);
        float v1 = fmaxf(q1 / ds - m1 * m1, 0.f);
        sd0 = sqrtf(v0 + EPSF); sd1 = sqrtf(v1 + EPSF);
        X0 = mx0; X1 = mx1; N0 = mn0; N1 = mn1;
    } else {
        m0 = m1 = sd0 = sd1 = X0 = X1 = N0 = N1 = 0.f;
    }
    unsigned* sp = (unsigned*)(stats + (size_t)n * 512);
    sp[lane]       = f2bf(m0) | (f2bf(m1) << 16);
    sp[64 + lane]  = f2bf(X0) | (f2bf(X1) << 16);
    sp[128 + lane] = f2bf(N0) | (f2bf(N1) << 16);
    sp[192 + lane] = f2bf(sd0) | (f2bf(sd1) << 16);
}

// ---------- out = [h|agg|agg*amp|agg*att] @ Wpost + bpost, * snorm  (MFMA, K=1664) ----------
__global__ __launch_bounds__(256) void k_gemm_post(
    const float* __restrict__ h, const float* __restrict__ snorm,
    const unsigned short* __restrict__ Wpt, const float* __restrict__ bpost,
    const unsigned short* __restrict__ stats, const int* __restrict__ base,
    float* __restrict__ out) {
    __shared__ __align__(16) unsigned short Asm[64 * 128];
    __shared__ __align__(16) unsigned short Bsm[128 * 128];
    __shared__ float sAmp[64], sAtt[64];
    const int t = threadIdx.x;
    const size_t row0 = (size_t)blockIdx.x * 64;

    if (t < 64) {
        size_t n = row0 + t;
        float a = 0.f, b = 0.f;
        if (n < NNODES) {
            int dg = base[n + 1] - base[n];
            a = logf((float)dg + 1.f) * (1.f / AVGDLOG);
            b = AVGDLOG / logf(fmaxf((float)dg, 1.f) + 1.f);
        }
        sAmp[t] = a; sAtt[t] = b;
    }

    const int w = t >> 6, lane = t & 63;
    const int lrow = lane & 15, lkb = lane >> 4;
    f32x4 acc[8];
#pragma unroll
    for (int i = 0; i < 8; ++i) acc[i] = (f32x4){0.f, 0.f, 0.f, 0.f};
    const char* Abase = (const char*)Asm + (w * 16 + lrow) * 256;
    const unsigned aswz = (unsigned)(((w * 16 + lrow) & 7) << 4);

    for (int s = 0; s < 13; ++s) {
        __syncthreads();
        // stage B chunk: Wpt[n][s*128 .. +128)
#pragma unroll
        for (int j = 0; j < 16; ++j) {
            int f = t + 256 * j;
            int n = f >> 5, q = f & 31;
            uint2 wv = *(const uint2*)(Wpt + (size_t)n * 1664 + s * 128 + q * 4);
            *(uint2*)((char*)Bsm + n * 256 + ((q * 8) ^ ((n & 7) << 4))) = wv;
        }
        // stage A chunk
        if (s == 0) {
#pragma unroll
            for (int j = 0; j < 8; ++j) {
                int f = t + 256 * j;
                int r = f >> 5, q = f & 31;
                size_t n = row0 + r;
                uint2 p = {0u, 0u};
                if (n < NNODES) {
                    float4 z = ((const float4*)h)[n * 32 + q];
                    p.x = f2bf(z.x) | (f2bf(z.y) << 16);
                    p.y = f2bf(z.z) | (f2bf(z.w) << 16);
                }
                *(uint2*)((char*)Asm + r * 256 + ((q * 8) ^ ((r & 7) << 4))) = p;
            }
        } else {
            const int seg = (s - 1) & 3, kind = (s - 1) >> 2;
#pragma unroll
            for (int j = 0; j < 8; ++j) {
                int f = t + 256 * j;
                int r = f >> 5, q = f & 31;
                size_t n = row0 + r;
                uint2 p = {0u, 0u};
                if (n < NNODES) {
                    uint2 sv = *(const uint2*)(stats + n * 512 + seg * 128 + q * 4);
                    if (kind == 0) {
                        p = sv;
                    } else {
                        float sc = (kind == 1) ? sAmp[r] : sAtt[r];
                        p.x = f2bf(bf2f(sv.x & 0xffffu) * sc) | (f2bf(bf2f(sv.x >> 16) * sc) << 16);
                        p.y = f2bf(bf2f(sv.y & 0xffffu) * sc) | (f2bf(bf2f(sv.y >> 16) * sc) << 16);
                    }
                }
                *(uint2*)((char*)Asm + r * 256 + ((q * 8) ^ ((r & 7) << 4))) = p;
            }
        }
        __syncthreads();
#pragma unroll
        for (int kk = 0; kk < 4; ++kk) {
            int kbyte = (kk * 32 + lkb * 8) * 2;
            short8 af = *(const short8*)(Abase + (kbyte ^ aswz));
#pragma unroll
            for (int nt = 0; nt < 8; ++nt) {
                int nn = nt * 16 + lrow;
                short8 bf = *(const short8*)((const char*)Bsm + nn * 256 + (kbyte ^ ((nn & 7) << 4)));
                acc[nt] = __builtin_amdgcn_mfma_f32_16x16x32_bf16(af, bf, acc[nt], 0, 0, 0);
            }
        }
    }
#pragma unroll
    for (int nt = 0; nt < 8; ++nt) {
        int c = nt * 16 + lrow;
        float bp = bpost[c];
#pragma unroll
        for (int i = 0; i < 4; ++i) {
            int lr = w * 16 + lkb * 4 + i;
            size_t grow = row0 + lr;
            if (grow < NNODES) {
                out[grow * 128 + c] = (acc[nt][i] + bp) * snorm[grow];
            }
        }
    }
}

extern "C" void kernel_launch(void* const* d_in, const int* in_sizes, int n_in,
                              void* d_out, int out_size, void* d_ws, size_t ws_size,
                              hipStream_t stream) {
    const float* h = (const float*)d_in[0];
    const float* e = (const float*)d_in[1];
    const float* snorm = (const float*)d_in[2];
    const int* src = (const int*)d_in[3];
    const int* dst = (const int*)d_in[4];
    const float* Wpre = (const float*)d_in[5];
    const float* bpre = (const float*)d_in[6];
    const float* Wpost = (const float*)d_in[7];
    const float* bpost = (const float*)d_in[8];
    float* out = (float*)d_out;

    char* p = (char*)d_ws;
    auto alloc = [&](size_t bytes) { char* r = p; p += (bytes + 255) & ~(size_t)255; return r; };
    unsigned short* P1 = (unsigned short*)alloc((size_t)NNODES * 128 * 2);
    unsigned short* P2 = (unsigned short*)alloc((size_t)NNODES * 128 * 2);
    unsigned short* stats = (unsigned short*)alloc((size_t)NNODES * 512 * 2);
    unsigned short* G = (unsigned short*)alloc((size_t)NEDGES * 128 * 2);
    unsigned short* W3t = (unsigned short*)alloc(128 * 128 * 2);
    unsigned short* Wpt = (unsigned short*)alloc((size_t)128 * 1664 * 2);
    unsigned* deg = (unsigned*)alloc((size_t)NNODES * 4);
    int* basep = (int*)alloc((size_t)(NNODES + 1) * 4);
    int* cursor = (int*)alloc((size_t)NNODES * 4);
    int* sorted = (int*)alloc((size_t)NEDGES * 4);

    k_zero<<<(NNODES + 255) / 256, 256, 0, stream>>>(deg);
    k_count<<<(NEDGES + 255) / 256, 256, 0, stream>>>(dst, deg);
    k_scan<<<1, 1024, 0, stream>>>(deg, basep, cursor);
    k_scatter<<<(NEDGES + 255) / 256, 256, 0, stream>>>(dst, cursor, sorted);
    k_convW<<<(128 * 1664 + 255) / 256, 256, 0, stream>>>(Wpre, Wpost, W3t, Wpt);
    k_p12<<<NNODES / 8, 256, 0, stream>>>(h, Wpre, P1, P2);
    k_gemm_e<<<NEDGES / 64, 256, 0, stream>>>(e, src, dst, W3t, bpre, P1, P2, G);
    k_reduce<<<NNODES / 4, 256, 0, stream>>>(G, basep, sorted, stats);
    k_gemm_post<<<(NNODES + 63) / 64, 256, 0, stream>>>(h, snorm, Wpt, bpost, stats, basep, out);
}

// Round 4
// 561.803 us; speedup vs baseline: 3.4614x; 1.4924x over previous
//
#include <hip/hip_runtime.h>
#include <math.h>

#define NNODES 50000
#define NEDGES 800000
#define AVGDLOG 2.833f
#define EPSF 1e-5f

typedef __attribute__((ext_vector_type(8))) short short8;
typedef __attribute__((ext_vector_type(4))) float f32x4;

__device__ __forceinline__ unsigned f2bf(float x) {
    unsigned u = __float_as_uint(x);
    return (u + 0x7FFFu + ((u >> 16) & 1u)) >> 16;
}
__device__ __forceinline__ float bf2f(unsigned lo16) {
    return __uint_as_float(lo16 << 16);
}
__device__ __forceinline__ void up8(uint4 v, float* f) {
    f[0] = bf2f(v.x & 0xffffu); f[1] = bf2f(v.x >> 16);
    f[2] = bf2f(v.y & 0xffffu); f[3] = bf2f(v.y >> 16);
    f[4] = bf2f(v.z & 0xffffu); f[5] = bf2f(v.z >> 16);
    f[6] = bf2f(v.w & 0xffffu); f[7] = bf2f(v.w >> 16);
}
__device__ __forceinline__ uint4 pk8(const float* f) {
    uint4 v;
    v.x = f2bf(f[0]) | (f2bf(f[1]) << 16);
    v.y = f2bf(f[2]) | (f2bf(f[3]) << 16);
    v.z = f2bf(f[4]) | (f2bf(f[5]) << 16);
    v.w = f2bf(f[6]) | (f2bf(f[7]) << 16);
    return v;
}

// ---------------- CSR ----------------
__global__ void k_zero(unsigned* __restrict__ deg) {
    int i = blockIdx.x * 256 + threadIdx.x;
    if (i < NNODES) deg[i] = 0u;
}
__global__ void k_count(const int* __restrict__ dst, unsigned* __restrict__ deg) {
    int i = blockIdx.x * 256 + threadIdx.x;
    if (i < NEDGES) atomicAdd(&deg[dst[i]], 1u);
}
__global__ __launch_bounds__(1024) void k_scan(const unsigned* __restrict__ deg,
                                               int* __restrict__ base, int* __restrict__ cursor) {
    __shared__ int ps[1024];
    const int t = threadIdx.x;
    const int CH = (NNODES + 1023) / 1024;
    int lo = t * CH, hi = min(lo + CH, NNODES);
    int s = 0;
    for (int i = lo; i < hi; ++i) s += (int)deg[i];
    ps[t] = s;
    __syncthreads();
    for (int off = 1; off < 1024; off <<= 1) {
        int v = (t >= off) ? ps[t - off] : 0;
        __syncthreads();
        ps[t] += v;
        __syncthreads();
    }
    int run = (t > 0) ? ps[t - 1] : 0;
    for (int i = lo; i < hi; ++i) {
        base[i] = run; cursor[i] = run;
        run += (int)deg[i];
    }
    if (t == 1023) base[NNODES] = run;
}
__global__ void k_scatter(const int* __restrict__ dst, const int* __restrict__ src,
                          int* __restrict__ cursor, int* __restrict__ sorted,
                          int* __restrict__ ssrc) {
    int i = blockIdx.x * 256 + threadIdx.x;
    if (i < NEDGES) {
        int d = dst[i];
        int slot = atomicAdd(&cursor[d], 1);
        sorted[slot] = i;
        ssrc[slot] = src[i];
    }
}

// ---------------- weight prep ----------------
__global__ void k_convW(const float* __restrict__ Wpre, const float* __restrict__ Wpost,
                        unsigned short* __restrict__ W3t, unsigned short* __restrict__ W12t,
                        unsigned short* __restrict__ Bhat) {
    int i = blockIdx.x * 256 + threadIdx.x;
    if (i < 128 * 128) {
        int n = i & 127, k = i >> 7;
        W3t[n * 128 + k] = (unsigned short)f2bf(Wpre[(256 + k) * 128 + n]);
    }
    if (i < 256 * 128) {
        int n = i >> 7, k = i & 127;
        float v = (n < 128) ? Wpre[k * 128 + n] : Wpre[(128 + k) * 128 + (n - 128)];
        W12t[n * 128 + k] = (unsigned short)f2bf(v);
    }
    if (i < 640 * 384) {
        int kc = i / (384 * 32);
        int rem = i % (384 * 32);
        int n = rem >> 5, kk = rem & 31;
        int k = kc * 32 + kk, c = n & 127, g = n >> 7;
        float v;
        if (g == 0) v = Wpost[k * 128 + c];
        else if (g == 1) v = (k < 128) ? 0.f : Wpost[(512 + k) * 128 + c];
        else v = (k < 128) ? 0.f : Wpost[(1024 + k) * 128 + c];
        Bhat[i] = (unsigned short)f2bf(v);
    }
}

// ---------------- P12 = h @ [W1|W2] (MFMA); also emits bf16(h) into Abuf[:,0:128] ----------------
__global__ __launch_bounds__(256) void k_p12(const float* __restrict__ h,
                                             const unsigned short* __restrict__ W12t,
                                             unsigned short* __restrict__ P1,
                                             unsigned short* __restrict__ P2,
                                             unsigned short* __restrict__ Abuf) {
    __shared__ __align__(16) unsigned short As[64 * 128];
    __shared__ __align__(16) unsigned short Bs[256 * 128];
    const int t = threadIdx.x;
    const size_t row0 = (size_t)blockIdx.x * 64;
#pragma unroll
    for (int j = 0; j < 16; ++j) {
        int idx = t + 256 * j;
        int n = idx >> 4, q = idx & 15;
        uint4 wv = *(const uint4*)(W12t + n * 128 + q * 8);
        *(uint4*)((char*)Bs + n * 256 + ((q * 16) ^ ((n & 7) << 4))) = wv;
    }
#pragma unroll
    for (int j = 0; j < 8; ++j) {
        int idx = t + 256 * j;
        int r = idx >> 5, q = idx & 31;
        size_t row = row0 + r;
        uint2 p = {0u, 0u};
        if (row < NNODES) {
            float4 z = ((const float4*)h)[row * 32 + q];
            p.x = f2bf(z.x) | (f2bf(z.y) << 16);
            p.y = f2bf(z.z) | (f2bf(z.w) << 16);
            *(uint2*)(Abuf + row * 640 + q * 4) = p;
        }
        *(uint2*)((char*)As + r * 256 + ((q * 8) ^ ((r & 7) << 4))) = p;
    }
    __syncthreads();
    const int w = t >> 6, lane = t & 63, lrow = lane & 15, lkb = lane >> 4;
    f32x4 acc[16];
#pragma unroll
    for (int i = 0; i < 16; ++i) acc[i] = (f32x4){0.f, 0.f, 0.f, 0.f};
    const char* Abase = (const char*)As + (w * 16 + lrow) * 256;
    const unsigned aswz = (unsigned)(((w * 16 + lrow) & 7) << 4);
#pragma unroll
    for (int kk = 0; kk < 4; ++kk) {
        int kbyte = (kk * 32 + lkb * 8) * 2;
        short8 af = *(const short8*)(Abase + (kbyte ^ aswz));
#pragma unroll
        for (int nt = 0; nt < 16; ++nt) {
            int n = nt * 16 + lrow;
            short8 bf = *(const short8*)((const char*)Bs + n * 256 + (kbyte ^ ((n & 7) << 4)));
            acc[nt] = __builtin_amdgcn_mfma_f32_16x16x32_bf16(af, bf, acc[nt], 0, 0, 0);
        }
    }
    // epilogue: scatter each 64x128 half into As, flush coalesced
#pragma unroll
    for (int half = 0; half < 2; ++half) {
        __syncthreads();
#pragma unroll
        for (int nt = 0; nt < 8; ++nt) {
            int c = nt * 16 + lrow;
#pragma unroll
            for (int i = 0; i < 4; ++i) {
                int lr = w * 16 + lkb * 4 + i;
                *(unsigned short*)((char*)As + lr * 256 + ((c * 2) ^ ((lr & 7) << 4))) =
                    (unsigned short)f2bf(acc[half * 8 + nt][i]);
            }
        }
        __syncthreads();
        unsigned short* dstP = half ? P2 : P1;
#pragma unroll
        for (int j = 0; j < 4; ++j) {  // 64 rows x 16 uint4 = 1024 = 256*4 (was 8: OOB bug)
            int idx = t + 256 * j;
            int r = idx >> 4, q = idx & 15;
            size_t row = row0 + r;
            if (row < NNODES) {
                uint4 v = *(const uint4*)((const char*)As + r * 256 + ((q * 16) ^ ((r & 7) << 4)));
                *(uint4*)(dstP + row * 128 + q * 8) = v;
            }
        }
    }
}

// ---------------- G[sorted slot] = bf16(e[eid] @ W3 + bpre) (MFMA) ----------------
__global__ __launch_bounds__(256) void k_gemm_e(const float* __restrict__ e,
                                                const int* __restrict__ sorted,
                                                const unsigned short* __restrict__ W3t,
                                                const float* __restrict__ bpre,
                                                unsigned short* __restrict__ G) {
    __shared__ __align__(16) unsigned short As[64 * 128];
    __shared__ __align__(16) unsigned short Bs[128 * 128];
    __shared__ int Seid[64];
    const int t = threadIdx.x;
    const size_t row0 = (size_t)blockIdx.x * 64;
    if (t < 64) Seid[t] = sorted[row0 + t];
    __syncthreads();
#pragma unroll
    for (int j = 0; j < 8; ++j) {
        int idx = t + 256 * j;
        int n = idx >> 4, q = idx & 15;
        uint4 wv = *(const uint4*)(W3t + n * 128 + q * 8);
        *(uint4*)((char*)Bs + n * 256 + ((q * 16) ^ ((n & 7) << 4))) = wv;
    }
#pragma unroll
    for (int j = 0; j < 8; ++j) {
        int idx = t + 256 * j;
        int r = idx >> 5, q = idx & 31;
        int eid = Seid[r];
        float4 z = ((const float4*)e)[(size_t)eid * 32 + q];
        uint2 p;
        p.x = f2bf(z.x) | (f2bf(z.y) << 16);
        p.y = f2bf(z.z) | (f2bf(z.w) << 16);
        *(uint2*)((char*)As + r * 256 + ((q * 8) ^ ((r & 7) << 4))) = p;
    }
    __syncthreads();
    const int w = t >> 6, lane = t & 63, lrow = lane & 15, lkb = lane >> 4;
    f32x4 acc[8];
#pragma unroll
    for (int i = 0; i < 8; ++i) acc[i] = (f32x4){0.f, 0.f, 0.f, 0.f};
    const char* Abase = (const char*)As + (w * 16 + lrow) * 256;
    const unsigned aswz = (unsigned)(((w * 16 + lrow) & 7) << 4);
#pragma unroll
    for (int kk = 0; kk < 4; ++kk) {
        int kbyte = (kk * 32 + lkb * 8) * 2;
        short8 af = *(const short8*)(Abase + (kbyte ^ aswz));
#pragma unroll
        for (int nt = 0; nt < 8; ++nt) {
            int n = nt * 16 + lrow;
            short8 bf = *(const short8*)((const char*)Bs + n * 256 + (kbyte ^ ((n & 7) << 4)));
            acc[nt] = __builtin_amdgcn_mfma_f32_16x16x32_bf16(af, bf, acc[nt], 0, 0, 0);
        }
    }
    // scatter to As (wave-local rows), then coalesced flush
#pragma unroll
    for (int nt = 0; nt < 8; ++nt) {
        int c = nt * 16 + lrow;
        float bp = bpre[c];
#pragma unroll
        for (int i = 0; i < 4; ++i) {
            int lr = w * 16 + lkb * 4 + i;
            *(unsigned short*)((char*)As + lr * 256 + ((c * 2) ^ ((lr & 7) << 4))) =
                (unsigned short)f2bf(acc[nt][i] + bp);
        }
    }
    __syncthreads();
#pragma unroll
    for (int j = 0; j < 4; ++j) {  // 64 rows x 16 uint4 = 1024 = 256*4 (was 8: OOB bug)
        int idx = t + 256 * j;
        int r = idx >> 4, q = idx & 15;
        uint4 v = *(const uint4*)((const char*)As + r * 256 + ((q * 16) ^ ((r & 7) << 4)));
        *(uint4*)(G + (row0 + r) * 128 + q * 8) = v;
    }
}

// ---------------- segmented reduce: m = G[slot] + P1[ssrc[slot]] + P2[n]; stats -> Abuf[:,128:640] ----------------
__global__ __launch_bounds__(256) void k_reduce(const unsigned short* __restrict__ G,
                                                const unsigned short* __restrict__ P1,
                                                const unsigned short* __restrict__ P2,
                                                const int* __restrict__ basep,
                                                const int* __restrict__ ssrc,
                                                unsigned short* __restrict__ Abuf) {
    const int t = threadIdx.x;
    const int n = blockIdx.x * 4 + (t >> 6);
    const int lane = t & 63, lq = lane >> 4, lc = lane & 15;
    int b0 = basep[n], b1 = basep[n + 1];
    int dg = b1 - b0;
    float s[8], q2[8], mx[8], mn[8];
#pragma unroll
    for (int j = 0; j < 8; ++j) { s[j] = 0.f; q2[j] = 0.f; mx[j] = -3.4e38f; mn[j] = 3.4e38f; }
    if (dg > 0) {
        float p2f[8];
        up8(*(const uint4*)(P2 + (size_t)n * 128 + lc * 8), p2f);
        for (int sl = b0 + lq; sl < b1; sl += 4) {
            int es = ssrc[sl];
            float gf[8], p1f[8];
            up8(*(const uint4*)(G + (size_t)sl * 128 + lc * 8), gf);
            up8(*(const uint4*)(P1 + (size_t)es * 128 + lc * 8), p1f);
#pragma unroll
            for (int j = 0; j < 8; ++j) {
                float m = gf[j] + p1f[j] + p2f[j];
                s[j] += m; q2[j] += m * m;
                mx[j] = fmaxf(mx[j], m); mn[j] = fminf(mn[j], m);
            }
        }
    }
#pragma unroll
    for (int off = 16; off <= 32; off <<= 1) {
#pragma unroll
        for (int j = 0; j < 8; ++j) {
            s[j] += __shfl_xor(s[j], off);
            q2[j] += __shfl_xor(q2[j], off);
            mx[j] = fmaxf(mx[j], __shfl_xor(mx[j], off));
            mn[j] = fminf(mn[j], __shfl_xor(mn[j], off));
        }
    }
    if (lane < 16) {
        float mean[8], sd[8], X[8], N[8];
        if (dg > 0) {
            float ds = (float)dg;
#pragma unroll
            for (int j = 0; j < 8; ++j) {
                mean[j] = s[j] / ds;
                float v = fmaxf(q2[j] / ds - mean[j] * mean[j], 0.f);
                sd[j] = sqrtf(v + EPSF);
                X[j] = mx[j]; N[j] = mn[j];
            }
        } else {
#pragma unroll
            for (int j = 0; j < 8; ++j) { mean[j] = 0.f; sd[j] = 0.f; X[j] = 0.f; N[j] = 0.f; }
        }
        unsigned short* row = Abuf + (size_t)n * 640 + 128 + lc * 8;
        *(uint4*)(row) = pk8(mean);
        *(uint4*)(row + 128) = pk8(X);
        *(uint4*)(row + 256) = pk8(N);
        *(uint4*)(row + 384) = pk8(sd);
    }
}

// ---------------- out = C0 + amp*C1 + att*C2 + b, *snorm ; C = A[50000,640] @ Bhat[640,384] ----------------
__global__ __launch_bounds__(512) void k_gemm_post(const unsigned short* __restrict__ Abuf,
                                                   const unsigned short* __restrict__ Bhat,
                                                   const float* __restrict__ bpost,
                                                   const float* __restrict__ snorm,
                                                   const int* __restrict__ basep,
                                                   float* __restrict__ out) {
    __shared__ __align__(16) unsigned short As[2][128 * 32];
    __shared__ __align__(16) unsigned short Bs[2][384 * 32];
    __shared__ float sAmp[128], sAtt[128], sSn[128], sBp[128];
    const int t = threadIdx.x;
    const size_t row0 = (size_t)blockIdx.x * 128;
    if (t < 128) {
        size_t nn = row0 + t;
        float a = 0.f, b = 0.f, sn = 0.f;
        if (nn < NNODES) {
            int dgi = basep[nn + 1] - basep[nn];
            a = logf((float)dgi + 1.f) * (1.f / AVGDLOG);
            b = AVGDLOG / logf(fmaxf((float)dgi, 1.f) + 1.f);
            sn = snorm[nn];
        }
        sAmp[t] = a; sAtt[t] = b; sSn[t] = sn; sBp[t] = bpost[t];
    }
    const int arow = t >> 2, ak4 = t & 3;
    auto loadA = [&](int kc, uint4& ra) {
        ra = (uint4){0u, 0u, 0u, 0u};
        if (row0 + arow < NNODES)
            ra = *(const uint4*)(Abuf + (row0 + arow) * 640 + kc * 32 + ak4 * 8);
    };
    auto loadB = [&](int kc, uint4* rb) {
#pragma unroll
        for (int j = 0; j < 3; ++j) {
            int idx = t + 512 * j;
            int n = idx >> 2, k4 = idx & 3;
            rb[j] = *(const uint4*)(Bhat + ((size_t)kc * 384 + n) * 32 + k4 * 8);
        }
    };
    auto storeLDS = [&](int buf, const uint4& ra, const uint4* rb) {
        *(uint4*)((char*)As[buf] + arow * 64 + ((ak4 * 16) ^ ((arow & 3) << 4))) = ra;
#pragma unroll
        for (int j = 0; j < 3; ++j) {
            int idx = t + 512 * j;
            int n = idx >> 2, k4 = idx & 3;
            *(uint4*)((char*)Bs[buf] + n * 64 + ((k4 * 16) ^ ((n & 3) << 4))) = rb[j];
        }
    };
    const int w = t >> 6, wm = w & 1, wn = w >> 1;
    const int lane = t & 63, lrow = lane & 15, lkb = lane >> 4;
    f32x4 acc[4][6];
#pragma unroll
    for (int a = 0; a < 4; ++a)
#pragma unroll
        for (int b = 0; b < 6; ++b) acc[a][b] = (f32x4){0.f, 0.f, 0.f, 0.f};

    uint4 ra, rb[3];
    loadA(0, ra); loadB(0, rb);
    storeLDS(0, ra, rb);
    int cur = 0;
    for (int kc = 0; kc < 20; ++kc) {
        if (kc < 19) { loadA(kc + 1, ra); loadB(kc + 1, rb); }
        __syncthreads();
        short8 af[4];
#pragma unroll
        for (int mi = 0; mi < 4; ++mi) {
            int r = wm * 64 + mi * 16 + lrow;
            af[mi] = *(const short8*)((const char*)As[cur] + r * 64 + ((lkb * 16) ^ ((r & 3) << 4)));
        }
        short8 bfv[6];
#pragma unroll
        for (int g = 0; g < 3; ++g)
#pragma unroll
            for (int j = 0; j < 2; ++j) {
                int nn = g * 128 + wn * 32 + j * 16 + lrow;
                bfv[g * 2 + j] = *(const short8*)((const char*)Bs[cur] + nn * 64 + ((lkb * 16) ^ ((nn & 3) << 4)));
            }
#pragma unroll
        for (int mi = 0; mi < 4; ++mi)
#pragma unroll
            for (int f = 0; f < 6; ++f)
                acc[mi][f] = __builtin_amdgcn_mfma_f32_16x16x32_bf16(af[mi], bfv[f], acc[mi][f], 0, 0, 0);
        if (kc < 19) storeLDS(cur ^ 1, ra, rb);
        cur ^= 1;
    }
#pragma unroll
    for (int mi = 0; mi < 4; ++mi)
#pragma unroll
        for (int j = 0; j < 2; ++j)
#pragma unroll
            for (int i = 0; i < 4; ++i) {
                int r = wm * 64 + mi * 16 + lkb * 4 + i;
                size_t grow = row0 + r;
                if (grow < NNODES) {
                    int c = wn * 32 + j * 16 + lrow;
                    float v = acc[mi][j][i] + sAmp[r] * acc[mi][2 + j][i] + sAtt[r] * acc[mi][4 + j][i] + sBp[c];
                    out[grow * 128 + c] = v * sSn[r];
                }
            }
}

extern "C" void kernel_launch(void* const* d_in, const int* in_sizes, int n_in,
                              void* d_out, int out_size, void* d_ws, size_t ws_size,
                              hipStream_t stream) {
    const float* h = (const float*)d_in[0];
    const float* e = (const float*)d_in[1];
    const float* snorm = (const float*)d_in[2];
    const int* src = (const int*)d_in[3];
    const int* dst = (const int*)d_in[4];
    const float* Wpre = (const float*)d_in[5];
    const float* bpre = (const float*)d_in[6];
    const float* Wpost = (const float*)d_in[7];
    const float* bpost = (const float*)d_in[8];
    float* out = (float*)d_out;

    char* p = (char*)d_ws;
    auto alloc = [&](size_t bytes) { char* r = p; p += (bytes + 255) & ~(size_t)255; return r; };
    unsigned short* P1 = (unsigned short*)alloc((size_t)NNODES * 128 * 2);
    unsigned short* P2 = (unsigned short*)alloc((size_t)NNODES * 128 * 2);
    unsigned short* Abuf = (unsigned short*)alloc((size_t)NNODES * 640 * 2);
    unsigned short* G = (unsigned short*)alloc((size_t)NEDGES * 128 * 2);
    unsigned short* W3t = (unsigned short*)alloc(128 * 128 * 2);
    unsigned short* W12t = (unsigned short*)alloc(256 * 128 * 2);
    unsigned short* Bhat = (unsigned short*)alloc((size_t)640 * 384 * 2);
    unsigned* deg = (unsigned*)alloc((size_t)NNODES * 4);
    int* basep = (int*)alloc((size_t)(NNODES + 1) * 4);
    int* cursor = (int*)alloc((size_t)NNODES * 4);
    int* sorted = (int*)alloc((size_t)NEDGES * 4);
    int* ssrc = (int*)alloc((size_t)NEDGES * 4);

    k_zero<<<(NNODES + 255) / 256, 256, 0, stream>>>(deg);
    k_count<<<(NEDGES + 255) / 256, 256, 0, stream>>>(dst, deg);
    k_scan<<<1, 1024, 0, stream>>>(deg, basep, cursor);
    k_scatter<<<(NEDGES + 255) / 256, 256, 0, stream>>>(dst, src, cursor, sorted, ssrc);
    k_convW<<<(640 * 384 + 255) / 256, 256, 0, stream>>>(Wpre, Wpost, W3t, W12t, Bhat);
    k_p12<<<(NNODES + 63) / 64, 256, 0, stream>>>(h, W12t, P1, P2, Abuf);
    k_gemm_e<<<NEDGES / 64, 256, 0, stream>>>(e, sorted, W3t, bpre, G);
    k_reduce<<<NNODES / 4, 256, 0, stream>>>(G, P1, P2, basep, ssrc, Abuf);
    k_gemm_post<<<(NNODES + 127) / 128, 512, 0, stream>>>(Abuf, Bhat, bpost, snorm, basep, out);
}

// Round 5
// 479.344 us; speedup vs baseline: 4.0568x; 1.1720x over previous
//
#include <hip/hip_runtime.h>
#include <math.h>

#define NNODES 50000
#define NEDGES 800000
#define AVGDLOG 2.833f
#define EPSF 1e-5f
#define TPB_E 8

typedef __attribute__((ext_vector_type(8))) short short8;
typedef __attribute__((ext_vector_type(4))) float f32x4;

__device__ __forceinline__ unsigned f2bf(float x) {
    unsigned u = __float_as_uint(x);
    return (u + 0x7FFFu + ((u >> 16) & 1u)) >> 16;
}
__device__ __forceinline__ float bf2f(unsigned lo16) {
    return __uint_as_float(lo16 << 16);
}
__device__ __forceinline__ void up8(uint4 v, float* f) {
    f[0] = bf2f(v.x & 0xffffu); f[1] = bf2f(v.x >> 16);
    f[2] = bf2f(v.y & 0xffffu); f[3] = bf2f(v.y >> 16);
    f[4] = bf2f(v.z & 0xffffu); f[5] = bf2f(v.z >> 16);
    f[6] = bf2f(v.w & 0xffffu); f[7] = bf2f(v.w >> 16);
}
__device__ __forceinline__ uint4 pk8(const float* f) {
    uint4 v;
    v.x = f2bf(f[0]) | (f2bf(f[1]) << 16);
    v.y = f2bf(f[2]) | (f2bf(f[3]) << 16);
    v.z = f2bf(f[4]) | (f2bf(f[5]) << 16);
    v.w = f2bf(f[6]) | (f2bf(f[7]) << 16);
    return v;
}

// ---------------- CSR ----------------
__global__ void k_zero(unsigned* __restrict__ deg) {
    int i = blockIdx.x * 256 + threadIdx.x;
    if (i < NNODES) deg[i] = 0u;
}
__global__ void k_count(const int* __restrict__ dst, unsigned* __restrict__ deg) {
    int i = blockIdx.x * 256 + threadIdx.x;
    if (i < NEDGES) atomicAdd(&deg[dst[i]], 1u);
}
__global__ __launch_bounds__(1024) void k_scan(const unsigned* __restrict__ deg,
                                               int* __restrict__ base, int* __restrict__ cursor) {
    __shared__ int ps[1024];
    const int t = threadIdx.x;
    const int lo = t * 52;
    int s = 0;
    if (lo + 52 <= NNODES) {
        const int4* dp = (const int4*)(deg + lo);
#pragma unroll
        for (int i = 0; i < 13; ++i) { int4 v = dp[i]; s += v.x + v.y + v.z + v.w; }
    } else {
        for (int i = lo; i < NNODES; ++i) s += (int)deg[i];
    }
    ps[t] = s;
    __syncthreads();
    for (int off = 1; off < 1024; off <<= 1) {
        int v = (t >= off) ? ps[t - off] : 0;
        __syncthreads();
        ps[t] += v;
        __syncthreads();
    }
    int run = (t > 0) ? ps[t - 1] : 0;
    if (lo + 52 <= NNODES) {
        const int4* dp = (const int4*)(deg + lo);
        int4* bp = (int4*)(base + lo);
        int4* cp = (int4*)(cursor + lo);
#pragma unroll
        for (int i = 0; i < 13; ++i) {
            int4 v = dp[i]; int4 b;
            b.x = run; run += v.x; b.y = run; run += v.y;
            b.z = run; run += v.z; b.w = run; run += v.w;
            bp[i] = b; cp[i] = b;
        }
    } else {
        for (int i = lo; i < NNODES; ++i) { base[i] = run; cursor[i] = run; run += (int)deg[i]; }
    }
    if (t == 1023) base[NNODES] = run;
}
__global__ void k_scatter(const int* __restrict__ dst, const int* __restrict__ src,
                          int* __restrict__ cursor, int* __restrict__ sorted,
                          int* __restrict__ ssrc) {
    int i = blockIdx.x * 256 + threadIdx.x;
    if (i < NEDGES) {
        int d = dst[i];
        int slot = atomicAdd(&cursor[d], 1);
        sorted[slot] = i;
        ssrc[slot] = src[i];
    }
}

// ---------------- weight prep ----------------
__global__ void k_convW(const float* __restrict__ Wpre, const float* __restrict__ Wpost,
                        unsigned short* __restrict__ W3t, unsigned short* __restrict__ W12t,
                        unsigned short* __restrict__ Bhat) {
    int i = blockIdx.x * 256 + threadIdx.x;
    if (i < 128 * 128) {
        int n = i & 127, k = i >> 7;
        W3t[n * 128 + k] = (unsigned short)f2bf(Wpre[(256 + k) * 128 + n]);
    }
    if (i < 256 * 128) {
        int n = i >> 7, k = i & 127;
        float v = (n < 128) ? Wpre[k * 128 + n] : Wpre[(128 + k) * 128 + (n - 128)];
        W12t[n * 128 + k] = (unsigned short)f2bf(v);
    }
    if (i < 640 * 384) {
        int kc = i / (384 * 32);
        int rem = i % (384 * 32);
        int n = rem >> 5, kk = rem & 31;
        int k = kc * 32 + kk, c = n & 127, g = n >> 7;
        float v;
        if (g == 0) v = Wpost[k * 128 + c];
        else if (g == 1) v = (k < 128) ? 0.f : Wpost[(512 + k) * 128 + c];
        else v = (k < 128) ? 0.f : Wpost[(1024 + k) * 128 + c];
        Bhat[i] = (unsigned short)f2bf(v);
    }
}

// ---------------- P12 = h @ [W1|W2] (MFMA); also emits bf16(h) into Abuf[:,0:128] ----------------
__global__ __launch_bounds__(256) void k_p12(const float* __restrict__ h,
                                             const unsigned short* __restrict__ W12t,
                                             unsigned short* __restrict__ P1,
                                             unsigned short* __restrict__ P2,
                                             unsigned short* __restrict__ Abuf) {
    __shared__ __align__(16) unsigned short As[64 * 128];
    __shared__ __align__(16) unsigned short Bs[256 * 128];
    const int t = threadIdx.x;
    const size_t row0 = (size_t)blockIdx.x * 64;
#pragma unroll
    for (int j = 0; j < 16; ++j) {
        int idx = t + 256 * j;
        int n = idx >> 4, q = idx & 15;
        uint4 wv = *(const uint4*)(W12t + n * 128 + q * 8);
        *(uint4*)((char*)Bs + n * 256 + ((q * 16) ^ ((n & 7) << 4))) = wv;
    }
#pragma unroll
    for (int j = 0; j < 8; ++j) {
        int idx = t + 256 * j;
        int r = idx >> 5, q = idx & 31;
        size_t row = row0 + r;
        uint2 p = {0u, 0u};
        if (row < NNODES) {
            float4 z = ((const float4*)h)[row * 32 + q];
            p.x = f2bf(z.x) | (f2bf(z.y) << 16);
            p.y = f2bf(z.z) | (f2bf(z.w) << 16);
            *(uint2*)(Abuf + row * 640 + q * 4) = p;
        }
        *(uint2*)((char*)As + r * 256 + ((q * 8) ^ ((r & 7) << 4))) = p;
    }
    __syncthreads();
    const int w = t >> 6, lane = t & 63, lrow = lane & 15, lkb = lane >> 4;
    f32x4 acc[16];
#pragma unroll
    for (int i = 0; i < 16; ++i) acc[i] = (f32x4){0.f, 0.f, 0.f, 0.f};
    const char* Abase = (const char*)As + (w * 16 + lrow) * 256;
    const unsigned aswz = (unsigned)(((w * 16 + lrow) & 7) << 4);
#pragma unroll
    for (int kk = 0; kk < 4; ++kk) {
        int kbyte = (kk * 32 + lkb * 8) * 2;
        short8 af = *(const short8*)(Abase + (kbyte ^ aswz));
#pragma unroll
        for (int nt = 0; nt < 16; ++nt) {
            int n = nt * 16 + lrow;
            short8 bf = *(const short8*)((const char*)Bs + n * 256 + (kbyte ^ ((n & 7) << 4)));
            acc[nt] = __builtin_amdgcn_mfma_f32_16x16x32_bf16(af, bf, acc[nt], 0, 0, 0);
        }
    }
#pragma unroll
    for (int half = 0; half < 2; ++half) {
        __syncthreads();
#pragma unroll
        for (int nt = 0; nt < 8; ++nt) {
            int c = nt * 16 + lrow;
#pragma unroll
            for (int i = 0; i < 4; ++i) {
                int lr = w * 16 + lkb * 4 + i;
                *(unsigned short*)((char*)As + lr * 256 + ((c * 2) ^ ((lr & 7) << 4))) =
                    (unsigned short)f2bf(acc[half * 8 + nt][i]);
            }
        }
        __syncthreads();
        unsigned short* dstP = half ? P2 : P1;
#pragma unroll
        for (int j = 0; j < 4; ++j) {
            int idx = t + 256 * j;
            int r = idx >> 4, q = idx & 15;
            size_t row = row0 + r;
            if (row < NNODES) {
                uint4 v = *(const uint4*)((const char*)As + r * 256 + ((q * 16) ^ ((r & 7) << 4)));
                *(uint4*)(dstP + row * 128 + q * 8) = v;
            }
        }
    }
}

// ---------------- G[sorted slot] = bf16(e[eid] @ W3 + bpre) (MFMA, pipelined multi-tile) ----------------
__global__ __launch_bounds__(256) void k_gemm_e(const float* __restrict__ e,
                                                const int* __restrict__ sorted,
                                                const unsigned short* __restrict__ W3t,
                                                const float* __restrict__ bpre,
                                                unsigned short* __restrict__ G) {
    __shared__ __align__(16) unsigned short Bs[128 * 128];   // persistent W3
    __shared__ __align__(16) unsigned short As[2][64 * 128]; // double-buffered A
    __shared__ int Seid[TPB_E * 64];
    const int t = threadIdx.x;
    const int tile0 = blockIdx.x * TPB_E;
    const int ntiles = min(TPB_E, 12500 - tile0);

    for (int j = t; j < TPB_E * 64; j += 256) {
        int slot = tile0 * 64 + j;
        Seid[j] = (slot < NEDGES) ? sorted[slot] : 0;
    }
    __syncthreads();

    const int q = t & 31, r5 = t >> 5;
    auto loadE = [&](int ti, float4* ra) {
#pragma unroll
        for (int j = 0; j < 8; ++j) {
            int r = r5 + 8 * j;
            int eid = Seid[ti * 64 + r];
            ra[j] = ((const float4*)e)[(size_t)eid * 32 + q];
        }
    };
    auto storeA = [&](int buf, const float4* ra) {
#pragma unroll
        for (int j = 0; j < 8; ++j) {
            int r = r5 + 8 * j;
            uint2 pv;
            pv.x = f2bf(ra[j].x) | (f2bf(ra[j].y) << 16);
            pv.y = f2bf(ra[j].z) | (f2bf(ra[j].w) << 16);
            *(uint2*)((char*)As[buf] + r * 256 + ((q * 8) ^ ((r & 7) << 4))) = pv;
        }
    };

    float4 ra[8];
    loadE(0, ra);
#pragma unroll
    for (int j = 0; j < 8; ++j) {
        int idx = t + 256 * j;
        int n = idx >> 4, qq = idx & 15;
        uint4 wv = *(const uint4*)(W3t + n * 128 + qq * 8);
        *(uint4*)((char*)Bs + n * 256 + ((qq * 16) ^ ((n & 7) << 4))) = wv;
    }
    storeA(0, ra);
    if (ntiles > 1) loadE(1, ra);
    __syncthreads();

    const int w = t >> 6, lane = t & 63, lrow = lane & 15, lkb = lane >> 4;
    float bpf[8];
#pragma unroll
    for (int nt = 0; nt < 8; ++nt) bpf[nt] = bpre[nt * 16 + lrow];

    for (int ti = 0; ti < ntiles; ++ti) {
        const int c = ti & 1;
        f32x4 acc[8];
#pragma unroll
        for (int i = 0; i < 8; ++i) acc[i] = (f32x4){0.f, 0.f, 0.f, 0.f};
        const char* Ab = (const char*)As[c] + (w * 16 + lrow) * 256;
        const unsigned aswz = (unsigned)(((w * 16 + lrow) & 7) << 4);
#pragma unroll
        for (int kk = 0; kk < 4; ++kk) {
            int kbyte = (kk * 32 + lkb * 8) * 2;
            short8 af = *(const short8*)(Ab + (kbyte ^ aswz));
#pragma unroll
            for (int nt = 0; nt < 8; ++nt) {
                int n = nt * 16 + lrow;
                short8 bf = *(const short8*)((const char*)Bs + n * 256 + (kbyte ^ ((n & 7) << 4)));
                acc[nt] = __builtin_amdgcn_mfma_f32_16x16x32_bf16(af, bf, acc[nt], 0, 0, 0);
            }
        }
        __syncthreads();  // (1) all MFMA reads of As[c] + prev flush reads of As[c^1] drained
        // scatter acc -> As[c] (transpose for coalesced flush)
#pragma unroll
        for (int nt = 0; nt < 8; ++nt) {
            int cc = nt * 16 + lrow;
#pragma unroll
            for (int i = 0; i < 4; ++i) {
                int lr = w * 16 + lkb * 4 + i;
                *(unsigned short*)((char*)As[c] + lr * 256 + ((cc * 2) ^ ((lr & 7) << 4))) =
                    (unsigned short)f2bf(acc[nt][i] + bpf[nt]);
            }
        }
        if (ti + 1 < ntiles) {
            storeA(c ^ 1, ra);                    // stage tile ti+1
            if (ti + 2 < ntiles) loadE(ti + 2, ra);  // issue gather for ti+2 (overlaps flush+next MFMA)
        }
        __syncthreads();  // (2) scatter + next-tile stage visible
        const size_t row0 = (size_t)(tile0 + ti) * 64;
#pragma unroll
        for (int j = 0; j < 4; ++j) {
            int idx = t + 256 * j;
            int r = idx >> 4, qq = idx & 15;
            uint4 v = *(const uint4*)((const char*)As[c] + r * 256 + ((qq * 16) ^ ((r & 7) << 4)));
            *(uint4*)(G + (row0 + r) * 128 + qq * 8) = v;
        }
    }
}

// ---------------- segmented reduce: m = G[slot] + P1[ssrc[slot]] + P2[n]; stats -> Abuf[:,128:640] ----------------
__global__ __launch_bounds__(256) void k_reduce(const unsigned short* __restrict__ G,
                                                const unsigned short* __restrict__ P1,
                                                const unsigned short* __restrict__ P2,
                                                const int* __restrict__ basep,
                                                const int* __restrict__ ssrc,
                                                unsigned short* __restrict__ Abuf) {
    const int t = threadIdx.x;
    const int n = blockIdx.x * 4 + (t >> 6);
    const int lane = t & 63, lq = lane >> 4, lc = lane & 15;
    int b0 = basep[n], b1 = basep[n + 1];
    int dg = b1 - b0;
    float s[8], q2[8], mx[8], mn[8];
#pragma unroll
    for (int j = 0; j < 8; ++j) { s[j] = 0.f; q2[j] = 0.f; mx[j] = -3.4e38f; mn[j] = 3.4e38f; }
    if (dg > 0) {
        float p2f[8];
        up8(*(const uint4*)(P2 + (size_t)n * 128 + lc * 8), p2f);
        for (int sl = b0 + lq; sl < b1; sl += 4) {
            int es = ssrc[sl];
            float gf[8], p1f[8];
            up8(*(const uint4*)(G + (size_t)sl * 128 + lc * 8), gf);
            up8(*(const uint4*)(P1 + (size_t)es * 128 + lc * 8), p1f);
#pragma unroll
            for (int j = 0; j < 8; ++j) {
                float m = gf[j] + p1f[j] + p2f[j];
                s[j] += m; q2[j] += m * m;
                mx[j] = fmaxf(mx[j], m); mn[j] = fminf(mn[j], m);
            }
        }
    }
#pragma unroll
    for (int off = 16; off <= 32; off <<= 1) {
#pragma unroll
        for (int j = 0; j < 8; ++j) {
            s[j] += __shfl_xor(s[j], off);
            q2[j] += __shfl_xor(q2[j], off);
            mx[j] = fmaxf(mx[j], __shfl_xor(mx[j], off));
            mn[j] = fminf(mn[j], __shfl_xor(mn[j], off));
        }
    }
    if (lane < 16) {
        float mean[8], sd[8], X[8], N[8];
        if (dg > 0) {
            float ds = (float)dg;
#pragma unroll
            for (int j = 0; j < 8; ++j) {
                mean[j] = s[j] / ds;
                float v = fmaxf(q2[j] / ds - mean[j] * mean[j], 0.f);
                sd[j] = sqrtf(v + EPSF);
                X[j] = mx[j]; N[j] = mn[j];
            }
        } else {
#pragma unroll
            for (int j = 0; j < 8; ++j) { mean[j] = 0.f; sd[j] = 0.f; X[j] = 0.f; N[j] = 0.f; }
        }
        unsigned short* row = Abuf + (size_t)n * 640 + 128 + lc * 8;
        *(uint4*)(row) = pk8(mean);
        *(uint4*)(row + 128) = pk8(X);
        *(uint4*)(row + 256) = pk8(N);
        *(uint4*)(row + 384) = pk8(sd);
    }
}

// ---------------- out = C0 + amp*C1 + att*C2 + b, *snorm ; C = A[50000,640] @ Bhat[640,384] ----------------
__global__ __launch_bounds__(512) void k_gemm_post(const unsigned short* __restrict__ Abuf,
                                                   const unsigned short* __restrict__ Bhat,
                                                   const float* __restrict__ bpost,
                                                   const float* __restrict__ snorm,
                                                   const int* __restrict__ basep,
                                                   float* __restrict__ out) {
    __shared__ __align__(16) unsigned short As[2][128 * 32];
    __shared__ __align__(16) unsigned short Bs[2][384 * 32];
    __shared__ float sAmp[128], sAtt[128], sSn[128], sBp[128];
    const int t = threadIdx.x;
    const size_t row0 = (size_t)blockIdx.x * 128;
    if (t < 128) {
        size_t nn = row0 + t;
        float a = 0.f, b = 0.f, sn = 0.f;
        if (nn < NNODES) {
            int dgi = basep[nn + 1] - basep[nn];
            a = logf((float)dgi + 1.f) * (1.f / AVGDLOG);
            b = AVGDLOG / logf(fmaxf((float)dgi, 1.f) + 1.f);
            sn = snorm[nn];
        }
        sAmp[t] = a; sAtt[t] = b; sSn[t] = sn; sBp[t] = bpost[t];
    }
    const int arow = t >> 2, ak4 = t & 3;
    auto loadA = [&](int kc, uint4& ra) {
        ra = (uint4){0u, 0u, 0u, 0u};
        if (row0 + arow < NNODES)
            ra = *(const uint4*)(Abuf + (row0 + arow) * 640 + kc * 32 + ak4 * 8);
    };
    auto loadB = [&](int kc, uint4* rb) {
#pragma unroll
        for (int j = 0; j < 3; ++j) {
            int idx = t + 512 * j;
            int n = idx >> 2, k4 = idx & 3;
            rb[j] = *(const uint4*)(Bhat + ((size_t)kc * 384 + n) * 32 + k4 * 8);
        }
    };
    auto storeLDS = [&](int buf, const uint4& ra, const uint4* rb) {
        *(uint4*)((char*)As[buf] + arow * 64 + ((ak4 * 16) ^ (((arow >> 1) & 3) << 4))) = ra;
#pragma unroll
        for (int j = 0; j < 3; ++j) {
            int idx = t + 512 * j;
            int n = idx >> 2, k4 = idx & 3;
            *(uint4*)((char*)Bs[buf] + n * 64 + ((k4 * 16) ^ (((n >> 1) & 3) << 4))) = rb[j];
        }
    };
    const int w = t >> 6, wm = w & 1, wn = w >> 1;
    const int lane = t & 63, lrow = lane & 15, lkb = lane >> 4;
    f32x4 acc[4][6];
#pragma unroll
    for (int a = 0; a < 4; ++a)
#pragma unroll
        for (int b = 0; b < 6; ++b) acc[a][b] = (f32x4){0.f, 0.f, 0.f, 0.f};

    uint4 ra, rb[3];
    loadA(0, ra); loadB(0, rb);
    storeLDS(0, ra, rb);
    int cur = 0;
    for (int kc = 0; kc < 20; ++kc) {
        if (kc < 19) { loadA(kc + 1, ra); loadB(kc + 1, rb); }
        __syncthreads();
        short8 af[4];
#pragma unroll
        for (int mi = 0; mi < 4; ++mi) {
            int r = wm * 64 + mi * 16 + lrow;
            af[mi] = *(const short8*)((const char*)As[cur] + r * 64 + ((lkb * 16) ^ (((r >> 1) & 3) << 4)));
        }
        short8 bfv[6];
#pragma unroll
        for (int g = 0; g < 3; ++g)
#pragma unroll
            for (int j = 0; j < 2; ++j) {
                int nn = g * 128 + wn * 32 + j * 16 + lrow;
                bfv[g * 2 + j] = *(const short8*)((const char*)Bs[cur] + nn * 64 + ((lkb * 16) ^ (((nn >> 1) & 3) << 4)));
            }
#pragma unroll
        for (int mi = 0; mi < 4; ++mi)
#pragma unroll
            for (int f = 0; f < 6; ++f)
                acc[mi][f] = __builtin_amdgcn_mfma_f32_16x16x32_bf16(af[mi], bfv[f], acc[mi][f], 0, 0, 0);
        if (kc < 19) storeLDS(cur ^ 1, ra, rb);
        cur ^= 1;
    }
#pragma unroll
    for (int mi = 0; mi < 4; ++mi)
#pragma unroll
        for (int j = 0; j < 2; ++j)
#pragma unroll
            for (int i = 0; i < 4; ++i) {
                int r = wm * 64 + mi * 16 + lkb * 4 + i;
                size_t grow = row0 + r;
                if (grow < NNODES) {
                    int c = wn * 32 + j * 16 + lrow;
                    float v = acc[mi][j][i] + sAmp[r] * acc[mi][2 + j][i] + sAtt[r] * acc[mi][4 + j][i] + sBp[c];
                    out[grow * 128 + c] = v * sSn[r];
                }
            }
}

extern "C" void kernel_launch(void* const* d_in, const int* in_sizes, int n_in,
                              void* d_out, int out_size, void* d_ws, size_t ws_size,
                              hipStream_t stream) {
    const float* h = (const float*)d_in[0];
    const float* e = (const float*)d_in[1];
    const float* snorm = (const float*)d_in[2];
    const int* src = (const int*)d_in[3];
    const int* dst = (const int*)d_in[4];
    const float* Wpre = (const float*)d_in[5];
    const float* bpre = (const float*)d_in[6];
    const float* Wpost = (const float*)d_in[7];
    const float* bpost = (const float*)d_in[8];
    float* out = (float*)d_out;

    char* p = (char*)d_ws;
    auto alloc = [&](size_t bytes) { char* r = p; p += (bytes + 255) & ~(size_t)255; return r; };
    unsigned short* P1 = (unsigned short*)alloc((size_t)NNODES * 128 * 2);
    unsigned short* P2 = (unsigned short*)alloc((size_t)NNODES * 128 * 2);
    unsigned short* Abuf = (unsigned short*)alloc((size_t)NNODES * 640 * 2);
    unsigned short* G = (unsigned short*)alloc((size_t)NEDGES * 128 * 2);
    unsigned short* W3t = (unsigned short*)alloc(128 * 128 * 2);
    unsigned short* W12t = (unsigned short*)alloc(256 * 128 * 2);
    unsigned short* Bhat = (unsigned short*)alloc((size_t)640 * 384 * 2);
    unsigned* deg = (unsigned*)alloc((size_t)NNODES * 4);
    int* basep = (int*)alloc((size_t)(NNODES + 1) * 4);
    int* cursor = (int*)alloc((size_t)NNODES * 4);
    int* sorted = (int*)alloc((size_t)NEDGES * 4);
    int* ssrc = (int*)alloc((size_t)NEDGES * 4);

    k_zero<<<(NNODES + 255) / 256, 256, 0, stream>>>(deg);
    k_count<<<(NEDGES + 255) / 256, 256, 0, stream>>>(dst, deg);
    k_scan<<<1, 1024, 0, stream>>>(deg, basep, cursor);
    k_scatter<<<(NEDGES + 255) / 256, 256, 0, stream>>>(dst, src, cursor, sorted, ssrc);
    k_convW<<<(640 * 384 + 255) / 256, 256, 0, stream>>>(Wpre, Wpost, W3t, W12t, Bhat);
    k_p12<<<(NNODES + 63) / 64, 256, 0, stream>>>(h, W12t, P1, P2, Abuf);
    k_gemm_e<<<(12500 + TPB_E - 1) / TPB_E, 256, 0, stream>>>(e, sorted, W3t, bpre, G);
    k_reduce<<<NNODES / 4, 256, 0, stream>>>(G, P1, P2, basep, ssrc, Abuf);
    k_gemm_post<<<(NNODES + 127) / 128, 512, 0, stream>>>(Abuf, Bhat, bpost, snorm, basep, out);
}